// Round 1
// baseline (127.160 us; speedup 1.0000x reference)
//
#include <hip/hip_runtime.h>

typedef __attribute__((ext_vector_type(8))) _Float16 f16x8;
typedef __attribute__((ext_vector_type(4))) float f32x4;

__device__ __forceinline__ f16x8 cvt8(f32x4 a, f32x4 b) {
  f16x8 h;
  h[0] = (_Float16)a.x; h[1] = (_Float16)a.y; h[2] = (_Float16)a.z; h[3] = (_Float16)a.w;
  h[4] = (_Float16)b.x; h[5] = (_Float16)b.y; h[6] = (_Float16)b.z; h[7] = (_Float16)b.w;
  return h;
}

// One wave = 16 batch elements. M-dim = batch, 6 nodes = 6 matmuls sharing W.
// Aggregation is per-lane on accumulators (identical C-frag layouts per node).
__global__ __launch_bounds__(256, 2) void gcn_fused(
    const float* __restrict__ x,
    const float* __restrict__ W1, const float* __restrict__ B1,
    const float* __restrict__ W2, const float* __restrict__ B2,
    const float* __restrict__ W3, const float* __restrict__ B3,
    const float* __restrict__ W4, const float* __restrict__ B4,
    const float* __restrict__ fcw, const float* __restrict__ fcb,
    float* __restrict__ out)
{
  // per-wave x_cur buffer for the inter-layer transpose; +8 f16 pad spreads banks
  __shared__ __align__(16) _Float16 xs[4][6][16][72];

  const int tid  = threadIdx.x;
  const int lane = tid & 63;
  const int wv   = tid >> 6;
  const int c    = lane & 15;   // MFMA: A-row / B-col / C-col
  const int q    = lane >> 4;   // MFMA: k-group / C row-group
  const int b0   = (blockIdx.x * 4 + wv) * 16;   // first batch element of this wave

  const float* Ws[4] = {W1, W2, W3, W4};
  const float* Bs[4] = {B1, B2, B3, B4};
  const int NB0[6] = {1, 0, 1, 2, 3, 3};
  const int NB1[6] = {2, 2, 3, 4, 5, 4};

  // ---- load x as layer-1 A-fragments + partial fc dot (residual folded) ----
  f16x8 xf[6][2];
  float pacc[6];
#pragma unroll
  for (int n = 0; n < 6; ++n) {
    float p = 0.f;
#pragma unroll
    for (int kt = 0; kt < 2; ++kt) {
      const float* src = x + (((b0 + c) * 6 + n) * 64 + kt * 32 + q * 8);
      f32x4 v0 = *(const f32x4*)src;
      f32x4 v1 = *(const f32x4*)(src + 4);
      const float* fw = fcw + (n * 64 + kt * 32 + q * 8);
      f32x4 w0 = *(const f32x4*)fw;
      f32x4 w1 = *(const f32x4*)(fw + 4);
      p += v0.x*w0.x + v0.y*w0.y + v0.z*w0.z + v0.w*w0.w
         + v1.x*w1.x + v1.y*w1.y + v1.z*w1.z + v1.w*w1.w;
      xf[n][kt] = cvt8(v0, v1);
    }
    // reduce the 4 k-groups (lanes c, c+16, c+32, c+48) -> full dot for b = b0+c
    p += __shfl_xor(p, 16, 64);
    p += __shfl_xor(p, 32, 64);
    pacc[n] = p;
  }

  f32x4 acc[6][4];

#pragma unroll
  for (int l = 0; l < 4; ++l) {
    const float* Wl = Ws[l];
    const float* bl = Bs[l];
    // B-fragments: B[k][n] = W[n][k]; lane: n = c (+16*nt), k = q*8+j (+32*kt)
    f16x8 wf[4][2];
    float bv[4];
#pragma unroll
    for (int nt = 0; nt < 4; ++nt) {
      bv[nt] = bl[nt * 16 + c];
#pragma unroll
      for (int kt = 0; kt < 2; ++kt) {
        const float* wsp = Wl + ((nt * 16 + c) * 64 + kt * 32 + q * 8);
        f32x4 a0 = *(const f32x4*)wsp;
        f32x4 a1 = *(const f32x4*)(wsp + 4);
        wf[nt][kt] = cvt8(a0, a1);
      }
    }
    const f32x4 z4 = {0.f, 0.f, 0.f, 0.f};
#pragma unroll
    for (int n = 0; n < 6; ++n) {
      f16x8 a0, a1;
      if (l == 0) { a0 = xf[n][0]; a1 = xf[n][1]; }
      else {
        a0 = *(const f16x8*)&xs[wv][n][c][q * 8];
        a1 = *(const f16x8*)&xs[wv][n][c][q * 8 + 32];
      }
#pragma unroll
      for (int nt = 0; nt < 4; ++nt) {
        f32x4 d = __builtin_amdgcn_mfma_f32_16x16x32_f16(a0, wf[nt][0], z4, 0, 0, 0);
        acc[n][nt] = __builtin_amdgcn_mfma_f32_16x16x32_f16(a1, wf[nt][1], d, 0, 0, 0);
      }
    }
    // ---- aggregation (per-lane!) + bias + relu, then LDS transpose write ----
    const float ca = (l < 2) ? (1.f / 3.f) : 0.5f;
    const float cb = (l < 2) ? (1.f / 3.f) : 0.25f;
#pragma unroll
    for (int nt = 0; nt < 4; ++nt) {
      f32x4 t[6];
#pragma unroll
      for (int n = 0; n < 6; ++n) {
        f32x4 s = acc[NB0[n]][nt] + acc[NB1[n]][nt];
        f32x4 r;
#pragma unroll
        for (int e = 0; e < 4; ++e)
          r[e] = fmaxf(0.f, ca * acc[n][nt][e] + cb * s[e] + bv[nt]);
        t[n] = r;
      }
#pragma unroll
      for (int n = 0; n < 6; ++n) {
        acc[n][nt] = t[n];
        if (l < 3) {
          // C-frag (col = nt*16+c, rows = 4q+e) -> x_cur[b][g] for next A-frags
#pragma unroll
          for (int e = 0; e < 4; ++e)
            xs[wv][n][q * 4 + e][nt * 16 + c] = (_Float16)t[n][e];
        }
      }
    }
  }

  // ---- epilogue: logits[b][n] = dot(h4, fc_w[n]) + partial_x + fc_b, sigmoid ----
#pragma unroll
  for (int n = 0; n < 6; ++n) {
    f32x4 sv = {0.f, 0.f, 0.f, 0.f};
#pragma unroll
    for (int nt = 0; nt < 4; ++nt) {
      const float fwv = fcw[n * 64 + nt * 16 + c];
      sv += acc[n][nt] * fwv;
    }
    // reduce over the 16 cols (c) within each row-group
#pragma unroll
    for (int m = 1; m <= 8; m <<= 1) {
      f32x4 o;
      o.x = __shfl_xor(sv.x, m, 64);
      o.y = __shfl_xor(sv.y, m, 64);
      o.z = __shfl_xor(sv.z, m, 64);
      o.w = __shfl_xor(sv.w, m, 64);
      sv += o;
    }
    const float fb = fcb[n];
#pragma unroll
    for (int e = 0; e < 4; ++e) {
      const float pb = __shfl(pacc[n], q * 4 + e, 64);  // partial_x for b = 4q+e
      const float zz = sv[e] + fb + pb;
      const float sg = 1.f / (1.f + __expf(-zz));
      if (c == n) out[(b0 + q * 4 + e) * 6 + n] = sg;
    }
  }
}

extern "C" void kernel_launch(void* const* d_in, const int* in_sizes, int n_in,
                              void* d_out, int out_size, void* d_ws, size_t ws_size,
                              hipStream_t stream) {
  const float* x   = (const float*)d_in[0];
  const float* W1  = (const float*)d_in[1];
  const float* B1  = (const float*)d_in[2];
  const float* W2  = (const float*)d_in[3];
  const float* B2  = (const float*)d_in[4];
  const float* W3  = (const float*)d_in[5];
  const float* B3  = (const float*)d_in[6];
  const float* W4  = (const float*)d_in[7];
  const float* B4  = (const float*)d_in[8];
  const float* fcw = (const float*)d_in[9];
  const float* fcb = (const float*)d_in[10];
  float* out = (float*)d_out;

  const int batch = in_sizes[0] / (6 * 64);   // 131072
  const int blocks = batch / 64;              // 4 waves * 16 elements per block
  hipLaunchKernelGGL(gcn_fused, dim3(blocks), dim3(256), 0, stream,
                     x, W1, B1, W2, B2, W3, B3, W4, B4, fcw, fcb, out);
}